// Round 2
// baseline (435.876 us; speedup 1.0000x reference)
//
#include <hip/hip_runtime.h>
#include <math.h>

// Problem constants
constexpr int Bc = 2, CGc = 64, Hc = 240, Wc = 1216;
constexpr int IDXR = 4, PROP = 6;
constexpr long HW  = (long)Hc * Wc;      // 291840
constexpr long BHW = (long)Bc * HW;      // 583680

// d_out layout (floats), outputs concatenated in return order:
// 0: disp (B,1,H,W)            @ OUT0, size BHW
// 1: list_disp (6,B,1,H,W)     @ OUT1, size 6*BHW
// 2: offset_flat (B,18,H,W)    @ OUT2
// 3: aff_full (B,9,H,W)        @ OUT3
// 4: aff_scale_const (1,)      @ OUT4
constexpr long OUT0 = 0;
constexpr long OUT1 = BHW;
constexpr long OUT2 = BHW * 7;
constexpr long OUT3 = OUT2 + (long)Bc * 18 * HW;
constexpr long OUT4 = OUT3 + (long)Bc * 9 * HW;

__device__ __forceinline__ float fetch_px(const float* __restrict__ img, int y, int x) {
  return (y >= 0 && y < Hc && x >= 0 && x < Wc) ? img[(long)y * Wc + x] : 0.f;
}

// bilinear sample with zero padding outside [0,H-1]x[0,W-1]
__device__ __forceinline__ float bilin(const float* __restrict__ img, float y, float x) {
  float y0f = floorf(y), x0f = floorf(x);
  int y0 = (int)y0f, x0 = (int)x0f;
  float wy = y - y0f, wx = x - x0f;
  float v00 = fetch_px(img, y0,     x0);
  float v01 = fetch_px(img, y0,     x0 + 1);
  float v10 = fetch_px(img, y0 + 1, x0);
  float v11 = fetch_px(img, y0 + 1, x0 + 1);
  float top = v00 + wx * (v01 - v00);
  float bot = v10 + wx * (v11 - v10);
  return top + wy * (bot - top);
}

// ---------------- conv3x3: guidance (B,64,H,W) -> 24 channels ----------------
// oa channel j = og*8+i.  j<16: neighbor n=j>>1, coord c=j&1 (0=y,1=x),
// post-ref-insertion slot m=(n<4?n:n+1) -> offset_flat channel 2m+c.
// j>=16: affinity i2=j-16 -> aff_full slot (i2<4?i2:i2+1).
__global__ __launch_bounds__(256) void conv_kernel(
    const float* __restrict__ g, const float* __restrict__ w,
    const float* __restrict__ bias, float* __restrict__ out) {
  constexpr int XT = Wc / 4;  // 304 tiles per row
  const int tile = blockIdx.x * 256 + threadIdx.x;
  if (tile >= Hc * XT) return;
  const int y  = tile / XT;
  const int x0 = (tile - y * XT) * 4;
  const int og = blockIdx.y;  // 0..2
  const int b  = blockIdx.z;  // 0..1

  const float* gb = g + (long)b * CGc * HW + (long)y * Wc + x0;
  float acc[8][4];
#pragma unroll
  for (int i = 0; i < 8; i++)
#pragma unroll
    for (int p = 0; p < 4; p++) acc[i][p] = 0.f;

  const bool interior = (y > 0) & (y < Hc - 1) & (x0 > 0) & (x0 < Wc - 4);
  const float* wbase = w + (long)og * 8 * CGc * 9;

  for (int ic = 0; ic < CGc; ic++) {
    float in[3][6];
    const float* p0 = gb + (long)ic * HW;
    if (interior) {
#pragma unroll
      for (int r = 0; r < 3; r++) {
        const float* row = p0 + (long)(r - 1) * Wc - 1;
#pragma unroll
        for (int c = 0; c < 6; c++) in[r][c] = row[c];
      }
    } else {
#pragma unroll
      for (int r = 0; r < 3; r++) {
        int yy = y + r - 1;
        bool yok = (yy >= 0) & (yy < Hc);
#pragma unroll
        for (int c = 0; c < 6; c++) {
          int xx = x0 - 1 + c;
          in[r][c] = (yok & (xx >= 0) & (xx < Wc)) ? p0[(long)(r - 1) * Wc - 1 + c] : 0.f;
        }
      }
    }
    const float* wp = wbase + (long)ic * 9;
#pragma unroll
    for (int i = 0; i < 8; i++) {
#pragma unroll
      for (int t = 0; t < 9; t++) {
        float wv = wp[(long)i * CGc * 9 + t];
        int r = t / 3, c = t % 3;
#pragma unroll
        for (int p = 0; p < 4; p++) acc[i][p] = fmaf(wv, in[r][c + p], acc[i][p]);
      }
    }
  }

#pragma unroll
  for (int i = 0; i < 8; i++) {
    float bv = bias[og * 8 + i];
    int j = og * 8 + i;
    long dst;
    if (j < 16) {
      int n = j >> 1, c = j & 1;
      int m = (n < IDXR) ? n : n + 1;
      dst = OUT2 + (long)(b * 18 + 2 * m + c) * HW;
    } else {
      int i2 = j - 16;
      int m = (i2 < IDXR) ? i2 : i2 + 1;
      dst = OUT3 + (long)(b * 9 + m) * HW;
    }
    float4 v = make_float4(acc[i][0] + bv, acc[i][1] + bv, acc[i][2] + bv, acc[i][3] + bv);
    *reinterpret_cast<float4*>(&out[dst + (long)y * Wc + x0]) = v;
  }
}

// ---------------- prep: tanh/scale, confidence sampling, normalization -------
__global__ __launch_bounds__(256) void prep_kernel(
    const float* __restrict__ conf, const float* __restrict__ scale_p,
    float* __restrict__ out) {
  long p = (long)blockIdx.x * 256 + threadIdx.x;
  if (p >= BHW) return;
  int b = (int)(p / HW);
  long rem = p - (long)b * HW;
  int y = (int)(rem / Wc);
  int x = (int)(rem - (long)y * Wc);

  const float inv_scale = 1.f / (scale_p[0] + 1e-8f);
  const float* confb = conf + (long)b * HW;
  float* off  = out + OUT2 + (long)b * 18 * HW + rem;
  float* affp = out + OUT3 + (long)b * 9  * HW + rem;

  float a[8];
  float asum = 0.f;
#pragma unroll
  for (int m = 0; m < 8; m++) {
    int n = (m < IDXR) ? m : m + 1;   // post-insertion slot of non-ref neighbor m
    float oy  = off[(long)(2 * n) * HW];
    float ox  = off[(long)(2 * n + 1) * HW];
    float raw = affp[(long)n * HW];
    float av  = tanhf(raw) * inv_scale;
    float cs  = bilin(confb, (float)y + oy, (float)x + ox);
    a[m] = av * cs;
    asum += fabsf(a[m]);
  }
  float s = fmaxf(asum + 1e-5f, 1.0f);
  float inv_s = 1.f / s;
  float total = 0.f;
#pragma unroll
  for (int m = 0; m < 8; m++) { a[m] *= inv_s; total += a[m]; }
  float aref = 1.f - total;
#pragma unroll
  for (int m = 0; m < 8; m++) {
    int n = (m < IDXR) ? m : m + 1;
    affp[(long)n * HW] = a[m];
  }
  affp[(long)IDXR * HW] = aref;
  // ref offset channels are identically zero
  off[(long)(2 * IDXR) * HW]     = 0.f;
  off[(long)(2 * IDXR + 1) * HW] = 0.f;
  if (p == 0) out[OUT4] = scale_p[0];
}

// ---------------- one propagation step --------------------------------------
__global__ __launch_bounds__(256) void prop_kernel(
    const float* __restrict__ dispPrev,  // (B,H,W)
    const float* __restrict__ occ, const float* __restrict__ initd,
    float* __restrict__ out, int t) {
  long p = (long)blockIdx.x * 256 + threadIdx.x;
  if (p >= BHW) return;
  int b = (int)(p / HW);
  long rem = p - (long)b * HW;
  int y = (int)(rem / Wc);
  int x = (int)(rem - (long)y * Wc);

  const float* off  = out + OUT2 + (long)b * 18 * HW + rem;
  const float* affp = out + OUT3 + (long)b * 9  * HW + rem;
  const float* db   = dispPrev + (long)b * HW;

  float acc = 0.f;
#pragma unroll
  for (int k = 0; k < 9; k++) {
    float oy = off[(long)(2 * k) * HW];
    float ox = off[(long)(2 * k + 1) * HW];
    float av = affp[(long)k * HW];
    float sy = (float)(y + k / 3 - 1) + oy;
    float sx = (float)(x + k % 3 - 1) + ox;
    acc = fmaf(av, bilin(db, sy, sx), acc);
  }
  acc = fmaxf(acc, 0.f);
  float o = occ[p];
  float res = (1.f - o) * acc + o * initd[p];
  out[OUT1 + (long)t * BHW + p] = res;
  if (t == PROP - 1) out[OUT0 + p] = res;
}

extern "C" void kernel_launch(void* const* d_in, const int* in_sizes, int n_in,
                              void* d_out, int out_size, void* d_ws, size_t ws_size,
                              hipStream_t stream) {
  const float* initd = (const float*)d_in[0];
  const float* occ   = (const float*)d_in[1];
  const float* conf  = (const float*)d_in[2];
  const float* guid  = (const float*)d_in[3];
  const float* cw    = (const float*)d_in[4];
  const float* cb    = (const float*)d_in[5];
  const float* csc   = (const float*)d_in[6];
  float* out = (float*)d_out;

  dim3 cgrid((Hc * (Wc / 4) + 255) / 256, 3, Bc);  // (285, 3, 2)
  conv_kernel<<<cgrid, 256, 0, stream>>>(guid, cw, cb, out);

  int nblk = (int)((BHW + 255) / 256);  // 2280
  prep_kernel<<<nblk, 256, 0, stream>>>(conf, csc, out);

  for (int t = 0; t < PROP; t++) {
    const float* dp = (t == 0) ? initd : (out + OUT1 + (long)(t - 1) * BHW);
    prop_kernel<<<nblk, 256, 0, stream>>>(dp, occ, initd, out, t);
  }
}

// Round 3
// 308.572 us; speedup vs baseline: 1.4126x; 1.4126x over previous
//
#include <hip/hip_runtime.h>
#include <hip/hip_bf16.h>
#include <math.h>

typedef __attribute__((ext_vector_type(8))) short bf16x8;
typedef __attribute__((ext_vector_type(4))) float f32x4;

// Problem constants
constexpr int Bc = 2, CGc = 64, Hc = 240, Wc = 1216;
constexpr int IDXR = 4, PROP = 6;
constexpr long HW  = (long)Hc * Wc;      // 291840
constexpr long BHW = (long)Bc * HW;      // 583680

// d_out layout (floats)
constexpr long OUT0 = 0;
constexpr long OUT1 = BHW;
constexpr long OUT2 = BHW * 7;
constexpr long OUT3 = OUT2 + (long)Bc * 18 * HW;
constexpr long OUT4 = OUT3 + (long)Bc * 9 * HW;

// conv tiling
constexpr int TY = 8, TX = 32;        // output tile per block
constexpr int AR = TY + 2, AC = TX + 2;  // staged input tile 10 x 34 (halo)
constexpr int A_BYTES = AR * AC * CGc * 2;   // 43520
constexpr int W_BYTES = 9 * 32 * 32 * 2;     // 18432 (one ic-half, oc padded to 32)

__device__ __forceinline__ unsigned short f2bf(float f) {
  __hip_bfloat16 h = __float2bfloat16(f);
  return __builtin_bit_cast(unsigned short, h);
}

__device__ __forceinline__ float fetch_px(const float* __restrict__ img, int y, int x) {
  return (y >= 0 && y < Hc && x >= 0 && x < Wc) ? img[(long)y * Wc + x] : 0.f;
}

__device__ __forceinline__ float bilin(const float* __restrict__ img, float y, float x) {
  float y0f = floorf(y), x0f = floorf(x);
  int y0 = (int)y0f, x0 = (int)x0f;
  float wy = y - y0f, wx = x - x0f;
  float v00 = fetch_px(img, y0,     x0);
  float v01 = fetch_px(img, y0,     x0 + 1);
  float v10 = fetch_px(img, y0 + 1, x0);
  float v11 = fetch_px(img, y0 + 1, x0 + 1);
  float top = v00 + wx * (v01 - v00);
  float bot = v10 + wx * (v11 - v10);
  return top + wy * (bot - top);
}

// ---------------- MFMA implicit-GEMM conv3x3 --------------------------------
// C[M=pixels, N=24(pad32)] = sum_{tap,ic} A[pixel, ic | tap-shift] * W[tap,ic,oc]
// A staged in LDS as [row10][col34][ic64] bf16 (ic innermost), XOR-swizzled.
// W staged per ic-half as [tap9][oc32][ic32] bf16, XOR-swizzled; oc rows 24-31
// uninitialized garbage -> contaminates only C cols 24-31, never stored.
__global__ __launch_bounds__(256) void conv_mfma_kernel(
    const float* __restrict__ g, const float* __restrict__ wsrc,
    const float* __restrict__ bias, float* __restrict__ out) {
  __shared__ __align__(16) char smemA[A_BYTES];
  __shared__ __align__(16) char smemW[W_BYTES];

  const int tid = threadIdx.x;
  const int x0 = blockIdx.x * TX;
  const int y0 = blockIdx.y * TY;
  const int bz = blockIdx.z;

  // ---- stage A: guidance tile -> bf16 LDS, ic pairs packed as u32 ----
  const float* gb = g + (long)bz * CGc * HW;
  for (int w = tid; w < AR * AC * 32; w += 256) {
    int c  = w % AC;
    int t2 = w / AC;
    int icp = t2 & 31;
    int r   = t2 >> 5;
    int y = y0 + r - 1, x = x0 + c - 1;
    float v0 = 0.f, v1 = 0.f;
    if (y >= 0 && y < Hc && x >= 0 && x < Wc) {
      const float* p = gb + (long)(2 * icp) * HW + (long)y * Wc + x;
      v0 = p[0];
      v1 = p[HW];
    }
    unsigned int pk = (unsigned int)f2bf(v0) | ((unsigned int)f2bf(v1) << 16);
    int byte = (r * AC + c) * 128 + icp * 4;
    byte ^= (c & 7) << 4;
    *reinterpret_cast<unsigned int*>(smemA + byte) = pk;
  }

  // ---- stage W (ic-half hs) ----
  auto stageW = [&](int hs) {
    for (int idx = tid; idx < 24 * 32 * 9; idx += 256) {
      int oc  = idx / 288;
      int r1  = idx - oc * 288;
      int icl = r1 / 9;
      int tap = r1 - icl * 9;
      float f = wsrc[idx + 288 * (oc + hs)];
      int byte = (tap * 32 + oc) * 64 + icl * 2;
      byte ^= (oc & 7) << 4;
      *reinterpret_cast<unsigned short*>(smemW + byte) = f2bf(f);
    }
  };
  stageW(0);
  __syncthreads();

  const int wid  = tid >> 6;
  const int lane = tid & 63;
  const int lrow = lane & 15;
  const int lgrp = lane >> 4;

  f32x4 acc[4][2];
#pragma unroll
  for (int m = 0; m < 4; m++)
#pragma unroll
    for (int nt = 0; nt < 2; nt++) acc[m][nt] = (f32x4){0.f, 0.f, 0.f, 0.f};

  for (int ks = 0; ks < 2; ++ks) {
    if (ks) {
      __syncthreads();   // everyone done reading half 0
      stageW(1);
      __syncthreads();
    }
#pragma unroll
    for (int tap = 0; tap < 9; ++tap) {
      const int dy = tap / 3, dx = tap - dy * 3;
      int bb = (tap * 32 + lrow) * 64 + lgrp * 16;
      int bbyte0 = bb ^ ((lrow & 7) << 4);
      int bbyte1 = (bb + 16 * 64) ^ ((lrow & 7) << 4);
      bf16x8 bf0 = *reinterpret_cast<const bf16x8*>(smemW + bbyte0);
      bf16x8 bf1 = *reinterpret_cast<const bf16x8*>(smemW + bbyte1);
#pragma unroll
      for (int dr = 0; dr < 2; ++dr) {
        const int rin = 2 * wid + dr + dy;
#pragma unroll
        for (int h = 0; h < 2; ++h) {
          const int cin = h * 16 + lrow + dx;
          int abyte = ((rin * AC + cin) * 128 + ks * 64 + lgrp * 16) ^ ((cin & 7) << 4);
          bf16x8 af = *reinterpret_cast<const bf16x8*>(smemA + abyte);
          acc[dr * 2 + h][0] = __builtin_amdgcn_mfma_f32_16x16x32_bf16(af, bf0, acc[dr * 2 + h][0], 0, 0, 0);
          acc[dr * 2 + h][1] = __builtin_amdgcn_mfma_f32_16x16x32_bf16(af, bf1, acc[dr * 2 + h][1], 0, 0, 0);
        }
      }
    }
  }

  // ---- epilogue: C[pixel, oc] -> d_out planes with channel remap ----
#pragma unroll
  for (int dr = 0; dr < 2; ++dr) {
    const int yy = y0 + 2 * wid + dr;
#pragma unroll
    for (int h = 0; h < 2; ++h) {
      const int xx = x0 + h * 16 + lgrp * 4;
#pragma unroll
      for (int nt = 0; nt < 2; ++nt) {
        int oc = nt * 16 + lrow;
        if (oc >= 24) continue;
        float bv = bias[oc];
        long dst;
        if (oc < 16) {
          int n = oc >> 1, cd = oc & 1;
          int mm = (n < IDXR) ? n : n + 1;
          dst = OUT2 + (long)(bz * 18 + 2 * mm + cd) * HW;
        } else {
          int i2 = oc - 16;
          int mm = (i2 < IDXR) ? i2 : i2 + 1;
          dst = OUT3 + (long)(bz * 9 + mm) * HW;
        }
        f32x4 v = acc[dr * 2 + h][nt];
        float4 st = make_float4(v[0] + bv, v[1] + bv, v[2] + bv, v[3] + bv);
        *reinterpret_cast<float4*>(&out[dst + (long)yy * Wc + xx]) = st;
      }
    }
  }
}

// ---------------- prep: tanh/scale, confidence sampling, normalization -------
__global__ __launch_bounds__(256) void prep_kernel(
    const float* __restrict__ conf, const float* __restrict__ scale_p,
    float* __restrict__ out) {
  long p = (long)blockIdx.x * 256 + threadIdx.x;
  if (p >= BHW) return;
  int b = (int)(p / HW);
  long rem = p - (long)b * HW;
  int y = (int)(rem / Wc);
  int x = (int)(rem - (long)y * Wc);

  const float inv_scale = 1.f / (scale_p[0] + 1e-8f);
  const float* confb = conf + (long)b * HW;
  float* off  = out + OUT2 + (long)b * 18 * HW + rem;
  float* affp = out + OUT3 + (long)b * 9  * HW + rem;

  float a[8];
  float asum = 0.f;
#pragma unroll
  for (int m = 0; m < 8; m++) {
    int n = (m < IDXR) ? m : m + 1;
    float oy  = off[(long)(2 * n) * HW];
    float ox  = off[(long)(2 * n + 1) * HW];
    float raw = affp[(long)n * HW];
    float av  = tanhf(raw) * inv_scale;
    float cs  = bilin(confb, (float)y + oy, (float)x + ox);
    a[m] = av * cs;
    asum += fabsf(a[m]);
  }
  float s = fmaxf(asum + 1e-5f, 1.0f);
  float inv_s = 1.f / s;
  float total = 0.f;
#pragma unroll
  for (int m = 0; m < 8; m++) { a[m] *= inv_s; total += a[m]; }
  float aref = 1.f - total;
#pragma unroll
  for (int m = 0; m < 8; m++) {
    int n = (m < IDXR) ? m : m + 1;
    affp[(long)n * HW] = a[m];
  }
  affp[(long)IDXR * HW] = aref;
  off[(long)(2 * IDXR) * HW]     = 0.f;
  off[(long)(2 * IDXR + 1) * HW] = 0.f;
  if (p == 0) out[OUT4] = scale_p[0];
}

// ---------------- one propagation step --------------------------------------
__global__ __launch_bounds__(256) void prop_kernel(
    const float* __restrict__ dispPrev,
    const float* __restrict__ occ, const float* __restrict__ initd,
    float* __restrict__ out, int t) {
  long p = (long)blockIdx.x * 256 + threadIdx.x;
  if (p >= BHW) return;
  int b = (int)(p / HW);
  long rem = p - (long)b * HW;
  int y = (int)(rem / Wc);
  int x = (int)(rem - (long)y * Wc);

  const float* off  = out + OUT2 + (long)b * 18 * HW + rem;
  const float* affp = out + OUT3 + (long)b * 9  * HW + rem;
  const float* db   = dispPrev + (long)b * HW;

  float acc = 0.f;
#pragma unroll
  for (int k = 0; k < 9; k++) {
    float oy = off[(long)(2 * k) * HW];
    float ox = off[(long)(2 * k + 1) * HW];
    float av = affp[(long)k * HW];
    float sy = (float)(y + k / 3 - 1) + oy;
    float sx = (float)(x + k % 3 - 1) + ox;
    acc = fmaf(av, bilin(db, sy, sx), acc);
  }
  acc = fmaxf(acc, 0.f);
  float o = occ[p];
  float res = (1.f - o) * acc + o * initd[p];
  out[OUT1 + (long)t * BHW + p] = res;
  if (t == PROP - 1) out[OUT0 + p] = res;
}

extern "C" void kernel_launch(void* const* d_in, const int* in_sizes, int n_in,
                              void* d_out, int out_size, void* d_ws, size_t ws_size,
                              hipStream_t stream) {
  const float* initd = (const float*)d_in[0];
  const float* occ   = (const float*)d_in[1];
  const float* conf  = (const float*)d_in[2];
  const float* guid  = (const float*)d_in[3];
  const float* cw    = (const float*)d_in[4];
  const float* cb    = (const float*)d_in[5];
  const float* csc   = (const float*)d_in[6];
  float* out = (float*)d_out;

  dim3 cgrid(Wc / TX, Hc / TY, Bc);  // (38, 30, 2)
  conv_mfma_kernel<<<cgrid, 256, 0, stream>>>(guid, cw, cb, out);

  int nblk = (int)((BHW + 255) / 256);  // 2280
  prep_kernel<<<nblk, 256, 0, stream>>>(conf, csc, out);

  for (int t = 0; t < PROP; t++) {
    const float* dp = (t == 0) ? initd : (out + OUT1 + (long)(t - 1) * BHW);
    prop_kernel<<<nblk, 256, 0, stream>>>(dp, occ, initd, out, t);
  }
}